// Round 1
// baseline (273.190 us; speedup 1.0000x reference)
//
#include <hip/hip_runtime.h>
#include <stdint.h>

#define C      1024
#define NH     16
#define HS     64
#define CT     65536
#define PAST   61440   // CT - WINDOW
#define KEEP   12288   // MIN_KV - WINDOW
#define NCHUNK 256
#define NCOMP  192     // KEEP/64
#define NSEL   32
#define CAND_CAP 16384

// descending-order monotone transform: float bits -> u32 such that
// larger float => smaller u (ascending u sort == descending value sort)
__device__ __forceinline__ unsigned int desc_key(float f) {
    unsigned int b = __float_as_uint(f);
    return (b >> 31) ? b : (~b & 0x7FFFFFFFu);
}

// ---------------- K1: q/k/v projections (row = dot(W[row,:], x)) -------------
__global__ void k_proj(const float* __restrict__ x, const float* __restrict__ Wr,
                       const float* __restrict__ Wk, const float* __restrict__ Wv,
                       float* __restrict__ q, float* __restrict__ kn, float* __restrict__ vn) {
    int w = blockIdx.x * (blockDim.x >> 6) + (threadIdx.x >> 6); // 0..3071
    int lane = threadIdx.x & 63;
    int mat = w >> 10, row = w & 1023;
    const float* W = (mat == 0) ? Wr : (mat == 1) ? Wk : Wv;
    const float4* Wrow = (const float4*)(W + (size_t)row * C);
    const float4* x4 = (const float4*)x;
    float acc = 0.f;
#pragma unroll
    for (int i = 0; i < 4; ++i) {
        float4 a = Wrow[i * 64 + lane];
        float4 b = x4[i * 64 + lane];
        acc += a.x * b.x + a.y * b.y + a.z * b.z + a.w * b.w;
    }
#pragma unroll
    for (int off = 32; off; off >>= 1) acc += __shfl_xor(acc, off);
    if (lane == 0) { (mat == 0 ? q : (mat == 1 ? kn : vn))[row] = acc; }
}

// ---------------- K2: per-head raw scores s[h][t] = qh . k_cache[t,h] --------
__global__ void k_scores(const float* __restrict__ kc, const float* __restrict__ q,
                         float* __restrict__ s) {
    int wid = blockIdx.x * (blockDim.x >> 6) + (threadIdx.x >> 6);
    int lane = threadIdx.x & 63;
    int nw = gridDim.x * (blockDim.x >> 6);
    const float4* q4 = (const float4*)q;
    float4 qv[4];
#pragma unroll
    for (int i = 0; i < 4; ++i) qv[i] = q4[i * 64 + lane];
    for (int t = wid; t < CT; t += nw) {
        const float4* row = (const float4*)(kc + (size_t)t * C);
        float acc[4];
#pragma unroll
        for (int i = 0; i < 4; ++i) {
            float4 a = row[i * 64 + lane];
            acc[i] = a.x * qv[i].x + a.y * qv[i].y + a.z * qv[i].z + a.w * qv[i].w;
        }
#pragma unroll
        for (int off = 8; off; off >>= 1) {
#pragma unroll
            for (int i = 0; i < 4; ++i) acc[i] += __shfl_xor(acc[i], off);
        }
        if ((lane & 15) == 0) {
            int g = lane >> 4;
#pragma unroll
            for (int i = 0; i < 4; ++i) s[(size_t)(4 * i + g) * CT + t] = acc[i];
        }
    }
}

// -------- K3: per-head select top-~12288 + exact stable sort (1 blk/head) ----
__global__ __launch_bounds__(1024) void k_sortsel(
        const float* __restrict__ s,
        unsigned long long* __restrict__ candA,
        unsigned long long* __restrict__ candB,
        unsigned short* __restrict__ sorted_tok) {
    __shared__ unsigned int hist[4096];
    __shared__ unsigned int wtot[16];
    __shared__ unsigned int wcnt[16][256];
    __shared__ unsigned int sh_rbase[256];
    __shared__ unsigned int sh_T12;
    __shared__ unsigned int sh_base;

    const int h = blockIdx.x;
    const int tid = threadIdx.x;
    const int lane = tid & 63;
    const int wave = tid >> 6;
    const float* sh_s = s + (size_t)h * CT;
    unsigned long long* A = candA + (size_t)h * CAND_CAP;
    unsigned long long* B = candB + (size_t)h * CAND_CAP;

    // ---- 12-bit histogram of desc keys over past tokens ----
    for (int j = tid; j < 4096; j += 1024) hist[j] = 0;
    __syncthreads();
    for (int t = tid; t < PAST; t += 1024) {
        unsigned int u = desc_key(sh_s[t]);
        atomicAdd(&hist[u >> 20], 1u);
    }
    __syncthreads();

    // ---- scan 4096 buckets, find threshold bucket T12 (cum >= KEEP) ----
    {
        unsigned int c0 = hist[tid * 4 + 0], c1 = hist[tid * 4 + 1];
        unsigned int c2 = hist[tid * 4 + 2], c3 = hist[tid * 4 + 3];
        unsigned int part = c0 + c1 + c2 + c3;
        unsigned int incl = part;
#pragma unroll
        for (int off = 1; off < 64; off <<= 1) {
            unsigned int n = __shfl_up(incl, off);
            if (lane >= off) incl += n;
        }
        if (lane == 63) wtot[wave] = incl;
        __syncthreads();
        unsigned int woff = 0;
        for (int w = 0; w < wave; ++w) woff += wtot[w];
        unsigned int excl = woff + incl - part;
        if (excl < KEEP && excl + part >= KEEP) {
            unsigned int run = excl, bsel;
            if (run + c0 >= KEEP) bsel = tid * 4;
            else if (run + c0 + c1 >= KEEP) bsel = tid * 4 + 1;
            else if (run + c0 + c1 + c2 >= KEEP) bsel = tid * 4 + 2;
            else bsel = tid * 4 + 3;
            sh_T12 = bsel;
        }
        __syncthreads();
    }
    const unsigned int T12 = sh_T12;

    // ---- ordered (index-stable) compaction of all tokens in buckets <= T12 ----
    if (tid == 0) sh_base = 0;
    __syncthreads();
    for (int tile = 0; tile < PAST / 1024; ++tile) {
        int t = tile * 1024 + tid;
        unsigned int u = desc_key(sh_s[t]);
        bool flag = (u >> 20) <= T12;
        unsigned long long m = __ballot(flag);
        unsigned int below = __popcll(m & ((1ull << lane) - 1ull));
        if (lane == 0) wtot[wave] = (unsigned int)__popcll(m);
        __syncthreads();
        unsigned int off = sh_base;
        for (int w = 0; w < wave; ++w) off += wtot[w];
        if (flag) {
            unsigned int p = off + below;
            if (p < CAND_CAP) A[p] = ((unsigned long long)u << 16) | (unsigned int)t;
        }
        __syncthreads();
        if (tid == 0) {
            unsigned int tt = 0;
            for (int w = 0; w < 16; ++w) tt += wtot[w];
            sh_base += tt;
        }
        __syncthreads();
    }
    unsigned int Ncand = sh_base;
    if (Ncand > CAND_CAP) Ncand = CAND_CAP;
    const int ntile = (int)((Ncand + 1023) >> 10);

    // ---- stable LSD radix sort on value bytes (bits 16..47 of packed) ----
    unsigned long long* src = A;
    unsigned long long* dst = B;
    for (int pass = 0; pass < 4; ++pass) {
        const int shift = 16 + 8 * pass;
        for (int j = tid; j < 256; j += 1024) hist[j] = 0;
        __syncthreads();
        for (int tile = 0; tile < ntile; ++tile) {
            int i = (tile << 10) + tid;
            bool valid = i < (int)Ncand;
            unsigned int d = valid ? ((unsigned int)(src[i] >> shift) & 255u) : 0u;
            unsigned long long eq = ~0ull;
#pragma unroll
            for (int bit = 0; bit < 8; ++bit) {
                unsigned long long bl = __ballot((d >> bit) & 1u);
                eq &= ((d >> bit) & 1u) ? bl : ~bl;
            }
            eq &= __ballot(valid);
            if (valid && __popcll(eq & ((1ull << lane) - 1ull)) == 0)
                atomicAdd(&hist[d], (unsigned int)__popcll(eq));
        }
        __syncthreads();
        if (tid == 0) {
            unsigned int run = 0;
            for (int j = 0; j < 256; ++j) { sh_rbase[j] = run; run += hist[j]; }
        }
        __syncthreads();
        for (int tile = 0; tile < ntile; ++tile) {
            int i = (tile << 10) + tid;
            bool valid = i < (int)Ncand;
            unsigned long long v = valid ? src[i] : 0ull;
            unsigned int d = (unsigned int)(v >> shift) & 255u;
            for (int j = tid; j < 16 * 256; j += 1024) ((unsigned int*)wcnt)[j] = 0;
            __syncthreads();
            unsigned long long eq = ~0ull;
#pragma unroll
            for (int bit = 0; bit < 8; ++bit) {
                unsigned long long bl = __ballot((d >> bit) & 1u);
                eq &= ((d >> bit) & 1u) ? bl : ~bl;
            }
            eq &= __ballot(valid);
            unsigned int wrank = (unsigned int)__popcll(eq & ((1ull << lane) - 1ull));
            if (valid && wrank == 0) wcnt[wave][d] = (unsigned int)__popcll(eq);
            __syncthreads();
            if (valid) {
                unsigned int woff = 0;
                for (int w = 0; w < wave; ++w) woff += wcnt[w][d];
                dst[sh_rbase[d] + woff + wrank] = v;
            }
            __syncthreads();
            for (int j = tid; j < 256; j += 1024) {
                unsigned int tt = 0;
#pragma unroll
                for (int w = 0; w < 16; ++w) tt += wcnt[w][j];
                sh_rbase[j] += tt;
            }
            __syncthreads();
        }
        unsigned long long* tmp = src; src = dst; dst = tmp;
    }
    // src now fully sorted by (value desc, idx asc); emit first KEEP token ids
    for (int r = tid; r < KEEP; r += 1024)
        sorted_tok[h * KEEP + r] = (unsigned short)(src[r] & 0xFFFFull);
}

// ---------------- K4: chunk scores = (1/64) sum over (h, j in chunk) of s ----
__global__ void k_chunkscore(const float* __restrict__ s,
                             const unsigned short* __restrict__ stok,
                             float* __restrict__ cs) {
    int c = blockIdx.x;          // 0..255
    int tid = threadIdx.x;       // 256
    __shared__ float red[256];
    float acc = 0.f;
    for (int p = tid; p < 64 * NH; p += 256) {
        int j = p & 63, hh = p >> 6;
        int t = (c < NCOMP) ? (int)stok[hh * KEEP + c * 64 + j]
                            : (PAST + (c - NCOMP) * 64 + j);
        acc += s[(size_t)hh * CT + t];
    }
    red[tid] = acc;
    __syncthreads();
    for (int st = 128; st; st >>= 1) {
        if (tid < st) red[tid] += red[tid + st];
        __syncthreads();
    }
    if (tid == 0) cs[c] = red[0] * (1.f / 64.f);
}

// ---------------- K4b: top-32 chunks via bitonic sort of 256 -----------------
__global__ void k_top32(const float* __restrict__ cs, unsigned int* __restrict__ sel) {
    __shared__ unsigned long long key[256];
    int tid = threadIdx.x;
    unsigned int u = desc_key(cs[tid]);
    key[tid] = ((unsigned long long)u << 32) | (unsigned int)tid;
    __syncthreads();
    for (unsigned k = 2; k <= 256; k <<= 1) {
        for (unsigned j = k >> 1; j > 0; j >>= 1) {
            unsigned ixj = tid ^ j;
            if (ixj > (unsigned)tid) {
                unsigned long long a = key[tid], b = key[ixj];
                bool up = ((tid & k) == 0);
                bool sw = up ? (a > b) : (a < b);
                if (sw) { key[tid] = b; key[ixj] = a; }
            }
            __syncthreads();
        }
    }
    if (tid < NSEL) sel[tid] = (unsigned int)(key[tid] & 0xFFFFFFFFull);
}

// ---------------- K5a: per (head, selected chunk) partial softmax+PV ---------
__global__ void k_attn_part(const float* __restrict__ s, const float* __restrict__ vc,
                            const unsigned short* __restrict__ stok,
                            const unsigned int* __restrict__ sel,
                            float* __restrict__ part) {
    int h = blockIdx.x >> 5, ci = blockIdx.x & 31;
    int tid = threadIdx.x;     // 256
    int g = tid >> 2, b3 = tid & 3;
    int c = (int)sel[ci];
    int t = (c < NCOMP) ? (int)stok[h * KEEP + c * 64 + g]
                        : (PAST + (c - NCOMP) * 64 + g);
    __shared__ float sc[64];
    __shared__ float ex[64];
    __shared__ float vbuf[64][65];
    if (b3 == 0) sc[g] = s[(size_t)h * CT + t] * 0.125f;
    __syncthreads();
    float m = -1e30f;
    for (int j = 0; j < 64; ++j) m = fmaxf(m, sc[j]);
    float e = expf(sc[g] - m);
    const float4* vrow = (const float4*)(vc + (size_t)t * C + h * HS);
#pragma unroll
    for (int it = 0; it < 4; ++it) {
        float4 vv = vrow[it * 4 + b3];
        int d0 = it * 16 + b3 * 4;
        vbuf[g][d0 + 0] = e * vv.x;
        vbuf[g][d0 + 1] = e * vv.y;
        vbuf[g][d0 + 2] = e * vv.z;
        vbuf[g][d0 + 3] = e * vv.w;
    }
    if (b3 == 0) ex[g] = e;
    __syncthreads();
    if (tid < 64) {
        float acc = 0.f;
        for (int g2 = 0; g2 < 64; ++g2) acc += vbuf[g2][tid];
        float* P = part + (size_t)(h * 32 + ci) * 68;
        P[2 + tid] = acc;
        if (tid == 0) {
            float es = 0.f;
            for (int g2 = 0; g2 < 64; ++g2) es += ex[g2];
            P[0] = m;
            P[1] = es;
        }
    }
}

// ---------------- K5b: combine partials + new token -> y ---------------------
__global__ void k_attn_fin(const float* __restrict__ part, const float* __restrict__ q,
                           const float* __restrict__ kn, const float* __restrict__ vn,
                           float* __restrict__ y) {
    int h = blockIdx.x;
    int lane = threadIdx.x;   // 64
    float qd = q[h * HS + lane] * kn[h * HS + lane];
#pragma unroll
    for (int off = 32; off; off >>= 1) qd += __shfl_xor(qd, off);
    float a_new = qd * 0.125f;
    const float* P0 = part + (size_t)h * 32 * 68;
    float m = a_new;
    for (int ci = 0; ci < 32; ++ci) m = fmaxf(m, P0[ci * 68]);
    float den = expf(a_new - m);
    float acc = den * vn[h * HS + lane];
    for (int ci = 0; ci < 32; ++ci) {
        float w = expf(P0[ci * 68] - m);
        den += w * P0[ci * 68 + 1];
        acc += w * P0[ci * 68 + 2 + lane];
    }
    y[h * HS + lane] = acc / den;
}

// ---------------- K6: out = y @ Wo.T -----------------------------------------
__global__ void k_out(const float* __restrict__ Wo, const float* __restrict__ y,
                      float* __restrict__ out) {
    int w = blockIdx.x * (blockDim.x >> 6) + (threadIdx.x >> 6); // 0..1023
    int lane = threadIdx.x & 63;
    const float4* Wrow = (const float4*)(Wo + (size_t)w * C);
    const float4* y4 = (const float4*)y;
    float acc = 0.f;
#pragma unroll
    for (int i = 0; i < 4; ++i) {
        float4 a = Wrow[i * 64 + lane];
        float4 b = y4[i * 64 + lane];
        acc += a.x * b.x + a.y * b.y + a.z * b.z + a.w * b.w;
    }
#pragma unroll
    for (int off = 32; off; off >>= 1) acc += __shfl_xor(acc, off);
    if (lane == 0) out[w] = acc;
}

extern "C" void kernel_launch(void* const* d_in, const int* in_sizes, int n_in,
                              void* d_out, int out_size, void* d_ws, size_t ws_size,
                              hipStream_t stream) {
    const float* x  = (const float*)d_in[0];
    const float* kc = (const float*)d_in[1];
    const float* vc = (const float*)d_in[2];
    const float* Wr = (const float*)d_in[3];
    const float* Wk = (const float*)d_in[4];
    const float* Wv = (const float*)d_in[5];
    const float* Wo = (const float*)d_in[6];
    float* out = (float*)d_out;
    char* ws = (char*)d_ws;

    float* q    = (float*)(ws + 0);
    float* kn   = (float*)(ws + 8192);
    float* vn   = (float*)(ws + 16384);
    float* y    = (float*)(ws + 24576);
    float* cs   = (float*)(ws + 32768);
    unsigned int* sel = (unsigned int*)(ws + 40960);
    float* part = (float*)(ws + 49152);                       // 139264 B
    unsigned short* stok = (unsigned short*)(ws + 196608);    // 393216 B
    float* s = (float*)(ws + 1048576);                        // 4 MiB
    unsigned long long* candA = (unsigned long long*)(ws + 5242880); // 2 MiB
    unsigned long long* candB = (unsigned long long*)(ws + 7340032); // 2 MiB

    k_proj<<<768, 256, 0, stream>>>(x, Wr, Wk, Wv, q, kn, vn);
    k_scores<<<2048, 256, 0, stream>>>(kc, q, s);
    k_sortsel<<<16, 1024, 0, stream>>>(s, candA, candB, stok);
    k_chunkscore<<<256, 256, 0, stream>>>(s, stok, cs);
    k_top32<<<1, 256, 0, stream>>>(cs, sel);
    k_attn_part<<<512, 256, 0, stream>>>(s, vc, stok, sel, part);
    k_attn_fin<<<16, 64, 0, stream>>>(part, q, kn, vn, y);
    k_out<<<256, 256, 0, stream>>>(Wo, y, out);
}

// Round 2
// 142.868 us; speedup vs baseline: 1.9122x; 1.9122x over previous
//
#include <hip/hip_runtime.h>
#include <stdint.h>

#define C      1024
#define NH     16
#define HS     64
#define CT     65536
#define PAST   61440   // CT - WINDOW
#define KEEP   12288   // MIN_KV - WINDOW
#define NCOMP  192     // KEEP/64
#define NSEL   32
#define NBINS  16384
#define CAP    16384

// monotone transform: larger float => smaller u (asc u == desc value)
__device__ __forceinline__ unsigned int desc_key(float f) {
    unsigned int b = __float_as_uint(f);
    return (b >> 31) ? b : (~b & 0x7FFFFFFFu);
}
__device__ __forceinline__ float u_to_f(unsigned int u) {
    unsigned int b = (u & 0x80000000u) ? u : (0x7FFFFFFFu - u);
    return __uint_as_float(b);
}
// monotone linear bin: s descending <-> bin ascending
__device__ __forceinline__ int bin_of(float s, float hi, float scale) {
    int b = (int)((hi - s) * scale);
    return b < 0 ? 0 : (b > NBINS - 1 ? NBINS - 1 : b);
}

// ---------------- K1: q/k/v projections -------------------------------------
__global__ void k_proj(const float* __restrict__ x, const float* __restrict__ Wr,
                       const float* __restrict__ Wk, const float* __restrict__ Wv,
                       float* __restrict__ q, float* __restrict__ kn, float* __restrict__ vn) {
    int w = blockIdx.x * (blockDim.x >> 6) + (threadIdx.x >> 6); // 0..3071
    int lane = threadIdx.x & 63;
    int mat = w >> 10, row = w & 1023;
    const float* W = (mat == 0) ? Wr : (mat == 1) ? Wk : Wv;
    const float4* Wrow = (const float4*)(W + (size_t)row * C);
    const float4* x4 = (const float4*)x;
    float acc = 0.f;
#pragma unroll
    for (int i = 0; i < 4; ++i) {
        float4 a = Wrow[i * 64 + lane];
        float4 b = x4[i * 64 + lane];
        acc += a.x * b.x + a.y * b.y + a.z * b.z + a.w * b.w;
    }
#pragma unroll
    for (int off = 32; off; off >>= 1) acc += __shfl_xor(acc, off);
    if (lane == 0) { (mat == 0 ? q : (mat == 1 ? kn : vn))[row] = acc; }
}

// ---------------- K2: per-head raw scores s[h][t] = qh . k_cache[t,h] --------
__global__ void k_scores(const float* __restrict__ kc, const float* __restrict__ q,
                         float* __restrict__ s) {
    int wid = blockIdx.x * (blockDim.x >> 6) + (threadIdx.x >> 6);
    int lane = threadIdx.x & 63;
    int nw = gridDim.x * (blockDim.x >> 6);
    const float4* q4 = (const float4*)q;
    float4 qv[4];
#pragma unroll
    for (int i = 0; i < 4; ++i) qv[i] = q4[i * 64 + lane];
    for (int t = wid; t < CT; t += nw) {
        const float4* row = (const float4*)(kc + (size_t)t * C);
        float acc[4];
#pragma unroll
        for (int i = 0; i < 4; ++i) {
            float4 a = row[i * 64 + lane];
            acc[i] = a.x * qv[i].x + a.y * qv[i].y + a.z * qv[i].z + a.w * qv[i].w;
        }
#pragma unroll
        for (int off = 8; off; off >>= 1) {
#pragma unroll
            for (int i = 0; i < 4; ++i) acc[i] += __shfl_xor(acc[i], off);
        }
        if ((lane & 15) == 0) {
            int g = lane >> 4;
#pragma unroll
            for (int i = 0; i < 4; ++i) s[(size_t)(4 * i + g) * CT + t] = acc[i];
        }
    }
}

// ---------------- S0: zero hist, init minmax ---------------------------------
__global__ __launch_bounds__(1024) void s0_init(unsigned* __restrict__ hist,
                                                unsigned* __restrict__ umin,
                                                unsigned* __restrict__ umax) {
    int id = blockIdx.x * 1024 + threadIdx.x;
    if (id < 16 * NBINS) hist[id] = 0;
    if (blockIdx.x == 0) {
        if (threadIdx.x < 16) umin[threadIdx.x] = 0xFFFFFFFFu;
        else if (threadIdx.x < 32) umax[threadIdx.x - 16] = 0u;
    }
}

// ---------------- S0b: per-head min/max of s over PAST -----------------------
__global__ void s0b_minmax(const float* __restrict__ s, unsigned* __restrict__ umin,
                           unsigned* __restrict__ umax) {
    __shared__ unsigned smin[4], smax[4];
    int h = blockIdx.x >> 4, seg = blockIdx.x & 15;
    int tid = threadIdx.x, lane = tid & 63, wave = tid >> 6;
    const float* sh = s + (size_t)h * CT + seg * 3840;
    unsigned mn = 0xFFFFFFFFu, mx = 0u;
    for (int i = tid; i < 3840; i += 256) {
        unsigned u = desc_key(sh[i]);
        mn = mn < u ? mn : u;
        mx = mx > u ? mx : u;
    }
#pragma unroll
    for (int off = 32; off; off >>= 1) {
        unsigned a = __shfl_xor(mn, off), b = __shfl_xor(mx, off);
        mn = mn < a ? mn : a;
        mx = mx > b ? mx : b;
    }
    if (lane == 0) { smin[wave] = mn; smax[wave] = mx; }
    __syncthreads();
    if (tid == 0) {
        mn = smin[0]; mx = smax[0];
        for (int w = 1; w < 4; ++w) {
            mn = mn < smin[w] ? mn : smin[w];
            mx = mx > smax[w] ? mx : smax[w];
        }
        atomicMin(&umin[h], mn);
        atomicMax(&umax[h], mx);
    }
}

// ---------------- S0c: derive hi/scale per head -------------------------------
__global__ void s0c_params(const unsigned* __restrict__ umin, const unsigned* __restrict__ umax,
                           float* __restrict__ hiArr, float* __restrict__ scArr) {
    int h = threadIdx.x;
    if (h >= 16) return;
    float hi = u_to_f(umin[h]);
    float lo = u_to_f(umax[h]);
    float r = hi - lo;
    scArr[h] = (r > 0.f) ? (float)(NBINS - 1) / r : 0.f;
    hiArr[h] = hi;
}

// ---------------- S1: linear-bin histogram over PAST --------------------------
__global__ __launch_bounds__(1024) void s1_hist(const float* __restrict__ s,
                                                unsigned* __restrict__ hist,
                                                const float* __restrict__ hiArr,
                                                const float* __restrict__ scArr) {
    __shared__ unsigned lh[NBINS];
    int h = blockIdx.x >> 2, seg = blockIdx.x & 3;
    int tid = threadIdx.x;
    for (int i = tid; i < NBINS; i += 1024) lh[i] = 0;
    __syncthreads();
    float hi = hiArr[h], sc = scArr[h];
    const float* sh = s + (size_t)h * CT + seg * 15360;
    for (int i = tid; i < 15360; i += 1024)
        atomicAdd(&lh[bin_of(sh[i], hi, sc)], 1u);
    __syncthreads();
    unsigned* gh = hist + h * NBINS;
    for (int i = tid; i < NBINS; i += 1024) {
        unsigned c = lh[i];
        if (c) atomicAdd(&gh[i], c);
    }
}

// ---------------- S2: exclusive scan + threshold bin T ------------------------
__global__ __launch_bounds__(1024) void s2_scan(unsigned* __restrict__ base,
                                                unsigned* __restrict__ Tarr) {
    __shared__ unsigned wsum[16];
    int h = blockIdx.x, tid = threadIdx.x, lane = tid & 63, wave = tid >> 6;
    unsigned* B = base + h * NBINS;
    unsigned cnt[16];
    unsigned loc = 0;
    int b0 = tid * 16;
#pragma unroll
    for (int k = 0; k < 16; ++k) { cnt[k] = B[b0 + k]; loc += cnt[k]; }
    unsigned run = loc;
#pragma unroll
    for (int off = 1; off < 64; off <<= 1) {
        unsigned n = __shfl_up(run, off);
        if (lane >= off) run += n;
    }
    if (lane == 63) wsum[wave] = run;
    __syncthreads();
    if (wave == 0 && lane < 16) {
        unsigned v = wsum[lane];
#pragma unroll
        for (int off = 1; off < 16; off <<= 1) {
            unsigned n = __shfl_up(v, off);
            if (lane >= off) v += n;
        }
        wsum[lane] = v;
    }
    __syncthreads();
    unsigned r = run - loc + (wave ? wsum[wave - 1] : 0u);
#pragma unroll
    for (int k = 0; k < 16; ++k) {
        unsigned c = cnt[k];
        B[b0 + k] = r;
        unsigned inc = r + c;
        if (r < KEEP && inc >= KEEP) Tarr[h] = (unsigned)(b0 + k);
        r = inc;
    }
}

// ---------------- S3: scatter candidates (bins <= T) into G -------------------
__global__ __launch_bounds__(1024) void s3_scatter(const float* __restrict__ s,
                                                   unsigned* __restrict__ base,
                                                   const unsigned* __restrict__ Tarr,
                                                   unsigned* __restrict__ G,
                                                   const float* __restrict__ hiArr,
                                                   const float* __restrict__ scArr) {
    int h = blockIdx.x / 60, seg = blockIdx.x % 60;
    int t = seg * 1024 + threadIdx.x;   // < 61440
    float v = s[(size_t)h * CT + t];
    int b = bin_of(v, hiArr[h], scArr[h]);
    if ((unsigned)b <= Tarr[h]) {
        unsigned pos = atomicAdd(&base[h * NBINS + b], 1u);
        if (pos < CAP) G[h * CAP + pos] = (unsigned)t;
    }
}

// ---------------- S4: exact rank via within-bin compare; emit sorted_tok ------
__global__ __launch_bounds__(1024) void s4_rank(const float* __restrict__ s,
                                                const unsigned* __restrict__ base,
                                                const unsigned* __restrict__ Tarr,
                                                const unsigned* __restrict__ G,
                                                const float* __restrict__ hiArr,
                                                const float* __restrict__ scArr,
                                                unsigned short* __restrict__ stok) {
    int h = blockIdx.x >> 4, seg = blockIdx.x & 15;
    int p = seg * 1024 + threadIdx.x;
    unsigned T = Tarr[h];
    unsigned ncand = base[h * NBINS + T];   // post-scatter: inclusive end of bin T
    if (ncand > CAP) ncand = CAP;
    if (p >= (int)ncand) return;
    unsigned tok = G[h * CAP + p];
    const float* sh = s + (size_t)h * CT;
    float v = sh[tok];
    unsigned u = desc_key(v);
    int b = bin_of(v, hiArr[h], scArr[h]);
    unsigned start = b ? base[h * NBINS + b - 1] : 0u;   // post-scatter end of bin b-1
    unsigned end = base[h * NBINS + b];
    if (end > CAP) end = CAP;
    unsigned rank = start;
    for (unsigned j = start; j < end; ++j) {
        unsigned t2 = G[h * CAP + j];
        unsigned u2 = desc_key(sh[t2]);
        rank += (u2 < u || (u2 == u && t2 < tok)) ? 1u : 0u;
    }
    if (rank < KEEP) stok[h * KEEP + rank] = (unsigned short)tok;
}

// ---------------- K4: chunk scores ------------------------------------------
__global__ void k_chunkscore(const float* __restrict__ s,
                             const unsigned short* __restrict__ stok,
                             float* __restrict__ cs) {
    int c = blockIdx.x;          // 0..255
    int tid = threadIdx.x;       // 256
    __shared__ float red[256];
    float acc = 0.f;
    for (int p = tid; p < 64 * NH; p += 256) {
        int j = p & 63, hh = p >> 6;
        int t = (c < NCOMP) ? (int)stok[hh * KEEP + c * 64 + j]
                            : (PAST + (c - NCOMP) * 64 + j);
        acc += s[(size_t)hh * CT + t];
    }
    red[tid] = acc;
    __syncthreads();
    for (int st = 128; st; st >>= 1) {
        if (tid < st) red[tid] += red[tid + st];
        __syncthreads();
    }
    if (tid == 0) cs[c] = red[0] * (1.f / 64.f);
}

// ---------------- K4b: top-32 chunks via bitonic sort of 256 -----------------
__global__ void k_top32(const float* __restrict__ cs, unsigned int* __restrict__ sel) {
    __shared__ unsigned long long key[256];
    int tid = threadIdx.x;
    unsigned int u = desc_key(cs[tid]);
    key[tid] = ((unsigned long long)u << 32) | (unsigned int)tid;
    __syncthreads();
    for (unsigned k = 2; k <= 256; k <<= 1) {
        for (unsigned j = k >> 1; j > 0; j >>= 1) {
            unsigned ixj = tid ^ j;
            if (ixj > (unsigned)tid) {
                unsigned long long a = key[tid], b = key[ixj];
                bool up = ((tid & k) == 0);
                bool sw = up ? (a > b) : (a < b);
                if (sw) { key[tid] = b; key[ixj] = a; }
            }
            __syncthreads();
        }
    }
    if (tid < NSEL) sel[tid] = (unsigned int)(key[tid] & 0xFFFFFFFFull);
}

// ---------------- K5a: per (head, selected chunk) partial softmax+PV ---------
__global__ void k_attn_part(const float* __restrict__ s, const float* __restrict__ vc,
                            const unsigned short* __restrict__ stok,
                            const unsigned int* __restrict__ sel,
                            float* __restrict__ part) {
    int h = blockIdx.x >> 5, ci = blockIdx.x & 31;
    int tid = threadIdx.x;     // 256
    int g = tid >> 2, b3 = tid & 3;
    int c = (int)sel[ci];
    int t = (c < NCOMP) ? (int)stok[h * KEEP + c * 64 + g]
                        : (PAST + (c - NCOMP) * 64 + g);
    __shared__ float sc[64];
    __shared__ float ex[64];
    __shared__ float vbuf[64][65];
    if (b3 == 0) sc[g] = s[(size_t)h * CT + t] * 0.125f;
    __syncthreads();
    float m = -1e30f;
    for (int j = 0; j < 64; ++j) m = fmaxf(m, sc[j]);
    float e = expf(sc[g] - m);
    const float4* vrow = (const float4*)(vc + (size_t)t * C + h * HS);
#pragma unroll
    for (int it = 0; it < 4; ++it) {
        float4 vv = vrow[it * 4 + b3];
        int d0 = it * 16 + b3 * 4;
        vbuf[g][d0 + 0] = e * vv.x;
        vbuf[g][d0 + 1] = e * vv.y;
        vbuf[g][d0 + 2] = e * vv.z;
        vbuf[g][d0 + 3] = e * vv.w;
    }
    if (b3 == 0) ex[g] = e;
    __syncthreads();
    if (tid < 64) {
        float acc = 0.f;
        for (int g2 = 0; g2 < 64; ++g2) acc += vbuf[g2][tid];
        float* P = part + (size_t)(h * 32 + ci) * 68;
        P[2 + tid] = acc;
        if (tid == 0) {
            float es = 0.f;
            for (int g2 = 0; g2 < 64; ++g2) es += ex[g2];
            P[0] = m;
            P[1] = es;
        }
    }
}

// ---------------- K5b: combine partials + new token -> y ---------------------
__global__ void k_attn_fin(const float* __restrict__ part, const float* __restrict__ q,
                           const float* __restrict__ kn, const float* __restrict__ vn,
                           float* __restrict__ y) {
    int h = blockIdx.x;
    int lane = threadIdx.x;   // 64
    float qd = q[h * HS + lane] * kn[h * HS + lane];
#pragma unroll
    for (int off = 32; off; off >>= 1) qd += __shfl_xor(qd, off);
    float a_new = qd * 0.125f;
    const float* P0 = part + (size_t)h * 32 * 68;
    float m = a_new;
    for (int ci = 0; ci < 32; ++ci) m = fmaxf(m, P0[ci * 68]);
    float den = expf(a_new - m);
    float acc = den * vn[h * HS + lane];
    for (int ci = 0; ci < 32; ++ci) {
        float w = expf(P0[ci * 68] - m);
        den += w * P0[ci * 68 + 1];
        acc += w * P0[ci * 68 + 2 + lane];
    }
    y[h * HS + lane] = acc / den;
}

// ---------------- K6: out = y @ Wo.T -----------------------------------------
__global__ void k_out(const float* __restrict__ Wo, const float* __restrict__ y,
                      float* __restrict__ out) {
    int w = blockIdx.x * (blockDim.x >> 6) + (threadIdx.x >> 6); // 0..1023
    int lane = threadIdx.x & 63;
    const float4* Wrow = (const float4*)(Wo + (size_t)w * C);
    const float4* y4 = (const float4*)y;
    float acc = 0.f;
#pragma unroll
    for (int i = 0; i < 4; ++i) {
        float4 a = Wrow[i * 64 + lane];
        float4 b = y4[i * 64 + lane];
        acc += a.x * b.x + a.y * b.y + a.z * b.z + a.w * b.w;
    }
#pragma unroll
    for (int off = 32; off; off >>= 1) acc += __shfl_xor(acc, off);
    if (lane == 0) out[w] = acc;
}

extern "C" void kernel_launch(void* const* d_in, const int* in_sizes, int n_in,
                              void* d_out, int out_size, void* d_ws, size_t ws_size,
                              hipStream_t stream) {
    const float* x  = (const float*)d_in[0];
    const float* kc = (const float*)d_in[1];
    const float* vc = (const float*)d_in[2];
    const float* Wr = (const float*)d_in[3];
    const float* Wk = (const float*)d_in[4];
    const float* Wv = (const float*)d_in[5];
    const float* Wo = (const float*)d_in[6];
    float* out = (float*)d_out;
    char* ws = (char*)d_ws;

    float* q    = (float*)(ws + 0);
    float* kn   = (float*)(ws + 8192);
    float* vn   = (float*)(ws + 16384);
    float* y    = (float*)(ws + 24576);
    float* cs   = (float*)(ws + 32768);
    unsigned int* sel = (unsigned int*)(ws + 40960);
    float* part = (float*)(ws + 49152);                       // 139264 B
    unsigned short* stok = (unsigned short*)(ws + 196608);    // 393216 B
    unsigned* umin  = (unsigned*)(ws + 655360);
    unsigned* umax  = (unsigned*)(ws + 655360 + 64);
    float*    hiArr = (float*)(ws + 655360 + 128);
    float*    scArr = (float*)(ws + 655360 + 192);
    unsigned* Tarr  = (unsigned*)(ws + 655360 + 256);
    float* s = (float*)(ws + 1048576);                        // 4 MiB
    unsigned* base = (unsigned*)(ws + 5242880);               // 1 MiB (hist -> scan -> counters)
    unsigned* G    = (unsigned*)(ws + 6291456);               // 1 MiB

    s0_init<<<256, 1024, 0, stream>>>(base, umin, umax);
    k_proj<<<768, 256, 0, stream>>>(x, Wr, Wk, Wv, q, kn, vn);
    k_scores<<<2048, 256, 0, stream>>>(kc, q, s);
    s0b_minmax<<<256, 256, 0, stream>>>(s, umin, umax);
    s0c_params<<<1, 64, 0, stream>>>(umin, umax, hiArr, scArr);
    s1_hist<<<64, 1024, 0, stream>>>(s, base, hiArr, scArr);
    s2_scan<<<16, 1024, 0, stream>>>(base, Tarr);
    s3_scatter<<<960, 1024, 0, stream>>>(s, base, Tarr, G, hiArr, scArr);
    s4_rank<<<256, 1024, 0, stream>>>(s, base, Tarr, G, hiArr, scArr, stok);
    k_chunkscore<<<256, 256, 0, stream>>>(s, stok, cs);
    k_top32<<<1, 256, 0, stream>>>(cs, sel);
    k_attn_part<<<512, 256, 0, stream>>>(s, vc, stok, sel, part);
    k_attn_fin<<<16, 64, 0, stream>>>(part, q, kn, vn, y);
    k_out<<<256, 256, 0, stream>>>(Wo, y, out);
}